// Round 4
// baseline (499.290 us; speedup 1.0000x reference)
//
#include <hip/hip_runtime.h>
#include <math.h>

#define D 128
#define LN_EPS 1e-5f
#define SCAN_CHUNK 1024
#define MT 64            // rows per block in dense kernel
#define WSTR 264         // LDS W row stride in ushorts (264*2=528B = 33*16B, breaks pow2 banks)

typedef unsigned int uint;
typedef unsigned short ushort;
typedef __attribute__((ext_vector_type(8))) short short8;
typedef __attribute__((ext_vector_type(4))) float floatx4;

__device__ __forceinline__ floatx4 mfma16(short8 a, short8 b, floatx4 c) {
    return __builtin_amdgcn_mfma_f32_16x16x32_bf16(a, b, c, 0, 0, 0);
}

// fp32 -> bf16 bits, round-nearest-even
__device__ __forceinline__ ushort f2bf(float f) {
    uint u = __float_as_uint(f);
    u += 0x7FFFu + ((u >> 16) & 1u);
    return (ushort)(u >> 16);
}

// ---------------- setup: zero cnt + W -> (hi,lo) bf16 pair + x -> bf16 ----------------
__global__ void setup_kernel(const float* __restrict__ x,
                             const float* __restrict__ Wl, const float* __restrict__ Wr,
                             ushort* __restrict__ xh, ushort* __restrict__ Whi,
                             ushort* __restrict__ Wlo, int* __restrict__ cnt,
                             int n_nodes) {
    const int t = blockIdx.x * blockDim.x + threadIdx.x;
    if (t * 4 < n_nodes)                       // n_nodes % 4 == 0
        *(int4*)&cnt[t * 4] = make_int4(0, 0, 0, 0);
    // Wcat[j][k]: k<128 -> Wl[j][k], else Wr[j][k-128]; hi/lo bf16 split
    if (t < 128 * 256) {
        int j = t >> 8, k = t & 255;
        float w = (k < 128) ? Wl[j * 128 + k] : Wr[j * 128 + (k - 128)];
        ushort hi = f2bf(w);
        float whif = __uint_as_float(((uint)hi) << 16);
        Whi[t] = hi;
        Wlo[t] = f2bf(w - whif);
    }
    // x -> bf16, 8 per thread
    int nconv = n_nodes * (D / 8);
    if (t < nconv) {
        int base = t * 8;
        float4 a = *(const float4*)&x[base];
        float4 b = *(const float4*)&x[base + 4];
        union { ushort h[8]; uint4 v; } pk;
        pk.h[0] = f2bf(a.x); pk.h[1] = f2bf(a.y); pk.h[2] = f2bf(a.z); pk.h[3] = f2bf(a.w);
        pk.h[4] = f2bf(b.x); pk.h[5] = f2bf(b.y); pk.h[6] = f2bf(b.z); pk.h[7] = f2bf(b.w);
        *(uint4*)&xh[base] = pk.v;
    }
}

// fallback-only: fp32 W transpose
__global__ void transpose_w(const float* __restrict__ Wl, const float* __restrict__ Wr,
                            float* __restrict__ WlT, float* __restrict__ WrT) {
    int t = blockIdx.x * blockDim.x + threadIdx.x;
    if (t < D * D) {
        int j = t & (D - 1);
        int k = t >> 7;
        WlT[k * D + j] = Wl[j * D + k];
        WrT[k * D + j] = Wr[j * D + k];
    }
}

// ---------------- histogram of dst ----------------
__global__ void hist_kernel(const int* __restrict__ dst, int* __restrict__ cnt, int E) {
    int e = blockIdx.x * blockDim.x + threadIdx.x;
    if (e < E) atomicAdd(&cnt[dst[e]], 1);
}

// ---------------- scan pass 1 ----------------
__global__ __launch_bounds__(256) void scan_partial(const int* __restrict__ cnt,
                                                    int* __restrict__ bsum, int n) {
    __shared__ int ws[4];
    const int tid = threadIdx.x;
    const int lane = tid & 63, wid = tid >> 6;
    int i0 = blockIdx.x * SCAN_CHUNK + tid * 4;
    int4 v = make_int4(0, 0, 0, 0);
    if (i0 < n) v = *(const int4*)&cnt[i0];
    int t = v.x + v.y + v.z + v.w;
    #pragma unroll
    for (int m = 32; m >= 1; m >>= 1) t += __shfl_xor(t, m);
    if (lane == 0) ws[wid] = t;
    __syncthreads();
    if (tid == 0) bsum[blockIdx.x] = ws[0] + ws[1] + ws[2] + ws[3];
}

// ---------------- scan pass 2 ----------------
__global__ __launch_bounds__(1024) void scan_base(const int* __restrict__ bsum,
                                                  int* __restrict__ bbase,
                                                  int* __restrict__ offsets,
                                                  int nb, int n) {
    __shared__ int wsums[16];
    const int tid = threadIdx.x;
    const int lane = tid & 63, wid = tid >> 6;
    int v = (tid < nb) ? bsum[tid] : 0;
    int s = v;
    #pragma unroll
    for (int off = 1; off < 64; off <<= 1) {
        int t = __shfl_up(s, off);
        if (lane >= off) s += t;
    }
    if (lane == 63) wsums[wid] = s;
    __syncthreads();
    if (tid < 16) {
        int w = wsums[tid];
        #pragma unroll
        for (int off = 1; off < 16; off <<= 1) {
            int t = __shfl_up(w, off);
            if (tid >= off) w += t;
        }
        wsums[tid] = w;
    }
    __syncthreads();
    int wprefix = (wid > 0) ? wsums[wid - 1] : 0;
    if (tid < nb) bbase[tid] = wprefix + (s - v);
    if (tid == 0) offsets[n] = wsums[15];
}

// ---------------- scan pass 3 (+cursor dual-write) ----------------
__global__ __launch_bounds__(256) void scan_final(const int* __restrict__ cnt,
                                                  const int* __restrict__ bbase,
                                                  int* __restrict__ offsets,
                                                  int* __restrict__ cursor, int n) {
    __shared__ int ws[4];
    __shared__ int wpre[4];
    const int tid = threadIdx.x;
    const int lane = tid & 63, wid = tid >> 6;
    int i0 = blockIdx.x * SCAN_CHUNK + tid * 4;
    int4 v = make_int4(0, 0, 0, 0);
    if (i0 < n) v = *(const int4*)&cnt[i0];
    int tsum = v.x + v.y + v.z + v.w;
    int s = tsum;
    #pragma unroll
    for (int off = 1; off < 64; off <<= 1) {
        int t = __shfl_up(s, off);
        if (lane >= off) s += t;
    }
    if (lane == 63) ws[wid] = s;
    __syncthreads();
    if (tid == 0) {
        int a = 0;
        #pragma unroll
        for (int i = 0; i < 4; i++) { wpre[i] = a; a += ws[i]; }
    }
    __syncthreads();
    if (i0 < n) {
        int excl = bbase[blockIdx.x] + wpre[wid] + (s - tsum);
        int4 o;
        o.x = excl;
        o.y = o.x + v.x;
        o.z = o.y + v.y;
        o.w = o.z + v.z;
        *(int4*)&offsets[i0] = o;
        *(int4*)&cursor[i0]  = o;
    }
}

// ---------------- fill CSR buckets ----------------
__global__ void fill_kernel(const int* __restrict__ src, const int* __restrict__ dst,
                            int* __restrict__ cursor, int* __restrict__ bucket, int E) {
    int e = blockIdx.x * blockDim.x + threadIdx.x;
    if (e < E) {
        int pos = atomicAdd(&cursor[dst[e]], 1);
        bucket[pos] = src[e];
    }
}

// ---------------- gather+mean: one wave per node, bf16 in/out ----------------
__global__ __launch_bounds__(256) void agg_kernel(
        const uint* __restrict__ xu,          // xh as uint[N][64] (2 bf16 each)
        const int* __restrict__ offsets, const int* __restrict__ bucket,
        uint* __restrict__ aggu, int n_nodes) {
    const int wave = threadIdx.x >> 6, lane = threadIdx.x & 63;
    const int g = blockIdx.x * 4 + wave;
    if (g >= n_nodes) return;
    const int o0 = offsets[g], o1 = offsets[g + 1];
    float s0 = 0.f, s1 = 0.f;
    int e = o0;
    for (; e + 8 <= o1; e += 8) {
        uint w[8];
        #pragma unroll
        for (int u = 0; u < 8; u++)
            w[u] = xu[(size_t)bucket[e + u] * 64 + lane];
        #pragma unroll
        for (int u = 0; u < 8; u++) {
            s0 += __uint_as_float(w[u] << 16);
            s1 += __uint_as_float(w[u] & 0xFFFF0000u);
        }
    }
    for (; e < o1; e++) {
        uint w = xu[(size_t)bucket[e] * 64 + lane];
        s0 += __uint_as_float(w << 16);
        s1 += __uint_as_float(w & 0xFFFF0000u);
    }
    int deg = o1 - o0;
    float inv = 1.f / (float)(deg > 0 ? deg : 1);
    aggu[(size_t)g * 64 + lane] = (uint)f2bf(s0 * inv) | (((uint)f2bf(s1 * inv)) << 16);
}

// ---------------- dense: MFMA GEMM [agg|x]·Wcat^T + bias + GELU + LN + residual ----------------
__global__ __launch_bounds__(256, 2) void dense_kernel(
        const ushort* __restrict__ aggh, const ushort* __restrict__ xh,
        const ushort* __restrict__ Whi,  const ushort* __restrict__ Wlo,
        const float* __restrict__ x,     const float* __restrict__ bl,
        const float* __restrict__ gam,   const float* __restrict__ bet,
        float* __restrict__ out, int n_nodes) {
    __shared__ ushort sW[128 * WSTR];   // 66 KB: W-hi, row-major [j][k], padded stride
    const int tid = threadIdx.x;
    // stage Whi into LDS (coalesced uint4)
    for (int i = tid; i < 128 * 32; i += 256) {
        int row = i >> 5, c8 = (i & 31) * 8;
        *(uint4*)&sW[row * WSTR + c8] = *(const uint4*)&Whi[row * 256 + c8];
    }
    __syncthreads();

    const int wave = tid >> 6, lane = tid & 63;
    const int lc = lane & 15, lq = lane >> 4;
    const int m0 = blockIdx.x * MT + wave * 16;   // this wave's 16 rows

    floatx4 acc[8];
    #pragma unroll
    for (int t = 0; t < 8; t++) acc[t] = (floatx4){0.f, 0.f, 0.f, 0.f};

    int arow = m0 + lc;                 // A-operand row for this lane
    if (arow >= n_nodes) arow = n_nodes - 1;
    const int koff = lq * 8;

    #pragma unroll
    for (int s = 0; s < 8; s++) {       // K = 256, 32 per step; s<4 = agg half, s>=4 = x half
        const ushort* aptr = (s < 4)
            ? (aggh + (size_t)arow * D + s * 32 + koff)
            : (xh   + (size_t)arow * D + (s - 4) * 32 + koff);
        short8 av = *(const short8*)aptr;
        #pragma unroll
        for (int t = 0; t < 8; t++) {
            short8 bh = *(const short8*)&sW[(t * 16 + lc) * WSTR + s * 32 + koff];
            acc[t] = mfma16(av, bh, acc[t]);
        }
        #pragma unroll
        for (int t = 0; t < 8; t++) {   // W-lo correction (from global, L2-hot)
            short8 bo = *(const short8*)&Wlo[(t * 16 + lc) * 256 + s * 32 + koff];
            acc[t] = mfma16(av, bo, acc[t]);
        }
    }

    // epilogue: bias + GELU + LN stats (C layout: row = lq*4+r, col = t*16+lc)
    float psum[4] = {0.f, 0.f, 0.f, 0.f};
    float psq[4]  = {0.f, 0.f, 0.f, 0.f};
    #pragma unroll
    for (int t = 0; t < 8; t++) {
        float bb = bl[t * 16 + lc];
        #pragma unroll
        for (int r = 0; r < 4; r++) {
            float f = acc[t][r] + bb;
            float g = 0.5f * f * (1.f + erff(f * 0.70710678118654752440f));
            acc[t][r] = g;
            psum[r] += g;
            psq[r]  += g * g;
        }
    }
    #pragma unroll
    for (int m = 8; m >= 1; m >>= 1) {
        #pragma unroll
        for (int r = 0; r < 4; r++) {
            psum[r] += __shfl_xor(psum[r], m);
            psq[r]  += __shfl_xor(psq[r], m);
        }
    }
    float mu[4], rs[4];
    #pragma unroll
    for (int r = 0; r < 4; r++) {
        mu[r] = psum[r] * (1.f / (float)D);
        float var = psq[r] * (1.f / (float)D) - mu[r] * mu[r];
        rs[r] = rsqrtf(var + LN_EPS);
    }
    #pragma unroll
    for (int t = 0; t < 8; t++) {
        int col = t * 16 + lc;
        float gm = gam[col], bt = bet[col];
        #pragma unroll
        for (int r = 0; r < 4; r++) {
            int row = m0 + lq * 4 + r;
            if (row < n_nodes) {
                float xr = x[(size_t)row * D + col];
                out[(size_t)row * D + col] = (acc[t][r] - mu[r]) * rs[r] * gm + bt + xr;
            }
        }
    }
}

// ---------------- fallback fused fp32 (proven R2 path) ----------------
#define NBF 32
#define LSTR 132
__global__ __launch_bounds__(256, 4) void fused_fb(
        const float* __restrict__ x,
        const float* __restrict__ WlT, const float* __restrict__ WrT,
        const float* __restrict__ bl,  const float* __restrict__ gam,
        const float* __restrict__ bet,
        const int* __restrict__ offsets, const int* __restrict__ bucket,
        float* __restrict__ out, int n_nodes) {
    __shared__ __align__(16) float sagg[NBF * LSTR];
    __shared__ __align__(16) float sx[NBF * LSTR];
    const int tid   = threadIdx.x;
    const int node0 = blockIdx.x * NBF;
    const int hl = tid & 31, hw = tid >> 5, hl4 = hl * 4;
    #pragma unroll
    for (int r = 0; r < NBF / 8; r++) {
        const int n = r * 8 + hw;
        const int g = node0 + n;
        float s0 = 0.f, s1 = 0.f, s2 = 0.f, s3 = 0.f;
        float4 xv = make_float4(0.f, 0.f, 0.f, 0.f);
        float inv = 0.f;
        if (g < n_nodes) {
            const int o0 = offsets[g], o1 = offsets[g + 1];
            int e = o0;
            for (; e + 4 <= o1; e += 4) {
                int i0 = bucket[e], i1 = bucket[e + 1], i2 = bucket[e + 2], i3 = bucket[e + 3];
                float4 a0 = *(const float4*)&x[i0 * D + hl4];
                float4 a1 = *(const float4*)&x[i1 * D + hl4];
                float4 a2 = *(const float4*)&x[i2 * D + hl4];
                float4 a3 = *(const float4*)&x[i3 * D + hl4];
                s0 += (a0.x + a1.x) + (a2.x + a3.x);
                s1 += (a0.y + a1.y) + (a2.y + a3.y);
                s2 += (a0.z + a1.z) + (a2.z + a3.z);
                s3 += (a0.w + a1.w) + (a2.w + a3.w);
            }
            for (; e < o1; e++) {
                float4 a = *(const float4*)&x[bucket[e] * D + hl4];
                s0 += a.x; s1 += a.y; s2 += a.z; s3 += a.w;
            }
            int deg = o1 - o0;
            inv = 1.f / (float)(deg > 0 ? deg : 1);
            xv = *(const float4*)&x[g * D + hl4];
        }
        *(float4*)&sagg[n * LSTR + hl4] = make_float4(s0 * inv, s1 * inv, s2 * inv, s3 * inv);
        *(float4*)&sx[n * LSTR + hl4]   = xv;
    }
    __syncthreads();
    const int tj = tid & 31, tn = tid >> 5;
    const int j0 = tj * 4, n0 = tn * 4;
    float4 blv = *(const float4*)&bl[j0];
    float acc[4][4];
    #pragma unroll
    for (int nn = 0; nn < 4; nn++) {
        acc[0][nn] = blv.x; acc[1][nn] = blv.y; acc[2][nn] = blv.z; acc[3][nn] = blv.w;
    }
    for (int kc = 0; kc < D; kc += 4) {
        float4 av[4], bv[4];
        #pragma unroll
        for (int nn = 0; nn < 4; nn++) {
            av[nn] = *(const float4*)&sagg[(n0 + nn) * LSTR + kc];
            bv[nn] = *(const float4*)&sx[(n0 + nn) * LSTR + kc];
        }
        #pragma unroll
        for (int kk = 0; kk < 4; kk++) {
            float4 wl = *(const float4*)&WlT[(kc + kk) * D + j0];
            float4 wr = *(const float4*)&WrT[(kc + kk) * D + j0];
            float wlv[4] = {wl.x, wl.y, wl.z, wl.w};
            float wrv[4] = {wr.x, wr.y, wr.z, wr.w};
            #pragma unroll
            for (int nn = 0; nn < 4; nn++) {
                float a = ((const float*)&av[nn])[kk];
                float b = ((const float*)&bv[nn])[kk];
                #pragma unroll
                for (int jj = 0; jj < 4; jj++)
                    acc[jj][nn] = fmaf(wlv[jj], a, fmaf(wrv[jj], b, acc[jj][nn]));
            }
        }
    }
    float psum[4] = {0.f, 0.f, 0.f, 0.f};
    float psq[4]  = {0.f, 0.f, 0.f, 0.f};
    #pragma unroll
    for (int jj = 0; jj < 4; jj++)
        #pragma unroll
        for (int nn = 0; nn < 4; nn++) {
            float f = acc[jj][nn];
            float g = 0.5f * f * (1.f + erff(f * 0.70710678118654752440f));
            acc[jj][nn] = g;
            psum[nn] += g;
            psq[nn]  += g * g;
        }
    #pragma unroll
    for (int m = 16; m >= 1; m >>= 1) {
        #pragma unroll
        for (int nn = 0; nn < 4; nn++) {
            psum[nn] += __shfl_xor(psum[nn], m);
            psq[nn]  += __shfl_xor(psq[nn], m);
        }
    }
    float4 gv = *(const float4*)&gam[j0];
    float4 bv4 = *(const float4*)&bet[j0];
    float gvv[4] = {gv.x, gv.y, gv.z, gv.w};
    float bvv[4] = {bv4.x, bv4.y, bv4.z, bv4.w};
    #pragma unroll
    for (int nn = 0; nn < 4; nn++) {
        int node = node0 + n0 + nn;
        if (node < n_nodes) {
            float m2  = psum[nn] * (1.f / (float)D);
            float var = psq[nn] * (1.f / (float)D) - m2 * m2;
            float rs  = rsqrtf(var + LN_EPS);
            float4 xr = *(const float4*)&x[node * D + j0];
            float xrv[4] = {xr.x, xr.y, xr.z, xr.w};
            float o[4];
            #pragma unroll
            for (int jj = 0; jj < 4; jj++)
                o[jj] = (acc[jj][nn] - m2) * rs * gvv[jj] + bvv[jj] + xrv[jj];
            *(float4*)&out[node * D + j0] = make_float4(o[0], o[1], o[2], o[3]);
        }
    }
}

static inline size_t align_up(size_t v, size_t a) { return (v + a - 1) & ~(a - 1); }

extern "C" void kernel_launch(void* const* d_in, const int* in_sizes, int n_in,
                              void* d_out, int out_size, void* d_ws, size_t ws_size,
                              hipStream_t stream) {
    const float* x   = (const float*)d_in[0];
    const int*   ei  = (const int*)d_in[1];
    const float* Wl  = (const float*)d_in[2];
    const float* bl  = (const float*)d_in[3];
    const float* Wr  = (const float*)d_in[4];
    const float* gam = (const float*)d_in[5];
    const float* bet = (const float*)d_in[6];
    float* out = (float*)d_out;

    const int N = in_sizes[0] / D;
    const int E = in_sizes[1] / 2;
    const int* src = ei;
    const int* dst = ei + E;
    const int nblk = (N + SCAN_CHUNK - 1) / SCAN_CHUNK;

    // workspace carve
    char* p = (char*)d_ws;
    int* cnt    = (int*)p;            // N
    int* cursor = cnt + N;            // N
    p = (char*)align_up((size_t)(cursor + N), 256);
    int* offsets = (int*)p;           // N+1
    p = (char*)align_up((size_t)(offsets + N + 1), 256);
    int* bucket = (int*)p;            // E
    p = (char*)align_up((size_t)(bucket + E), 256);
    ushort* Whi = (ushort*)p;         // 128*256 (64 KB)  [fallback overlays WlT/WrT fp32 here]
    ushort* Wlo = Whi + 128 * 256;    // 64 KB
    float* WlT = (float*)Whi;         // fallback view
    float* WrT = WlT + D * D;
    p = (char*)align_up((size_t)(Wlo + 128 * 256), 256);
    int* bsum  = (int*)p;
    int* bbase = bsum + 1024;
    p = (char*)align_up((size_t)(bbase + 1024), 256);
    ushort* xh   = (ushort*)p;        // N*128 bf16 (25.6 MB)
    ushort* aggh = xh + (size_t)N * D;// N*128 bf16 (25.6 MB)
    size_t need_full = (size_t)((char*)(aggh + (size_t)N * D) - (char*)d_ws);
    const bool full = (ws_size >= need_full);

    if (full) {
        const int setup_threads = N * (D / 8);   // covers W (32768) and cnt (N/4) too
        setup_kernel<<<(setup_threads + 255) / 256, 256, 0, stream>>>(
            x, Wl, Wr, xh, Whi, Wlo, cnt, N);
        hist_kernel<<<(E + 255) / 256, 256, 0, stream>>>(dst, cnt, E);
        scan_partial<<<nblk, 256, 0, stream>>>(cnt, bsum, N);
        scan_base<<<1, 1024, 0, stream>>>(bsum, bbase, offsets, nblk, N);
        scan_final<<<nblk, 256, 0, stream>>>(cnt, bbase, offsets, cursor, N);
        fill_kernel<<<(E + 255) / 256, 256, 0, stream>>>(src, dst, cursor, bucket, E);
        agg_kernel<<<(N + 3) / 4, 256, 0, stream>>>(
            (const uint*)xh, offsets, bucket, (uint*)aggh, N);
        dense_kernel<<<(N + MT - 1) / MT, 256, 0, stream>>>(
            aggh, xh, Whi, Wlo, x, bl, gam, bet, out, N);
    } else {
        // fallback: proven fp32 fused path (small ws)
        hipMemsetAsync(cnt, 0, (size_t)N * sizeof(int), stream);
        transpose_w<<<(D * D + 255) / 256, 256, 0, stream>>>(Wl, Wr, WlT, WrT);
        hist_kernel<<<(E + 255) / 256, 256, 0, stream>>>(dst, cnt, E);
        scan_partial<<<nblk, 256, 0, stream>>>(cnt, bsum, N);
        scan_base<<<1, 1024, 0, stream>>>(bsum, bbase, offsets, nblk, N);
        scan_final<<<nblk, 256, 0, stream>>>(cnt, bbase, offsets, cursor, N);
        fill_kernel<<<(E + 255) / 256, 256, 0, stream>>>(src, dst, cursor, bucket, E);
        fused_fb<<<(N + NBF - 1) / NBF, 256, 0, stream>>>(
            x, WlT, WrT, bl, gam, bet, offsets, bucket, out, N);
    }
}

// Round 5
// 428.712 us; speedup vs baseline: 1.1646x; 1.1646x over previous
//
#include <hip/hip_runtime.h>
#include <math.h>

#define D 128
#define LN_EPS 1e-5f
#define SCAN_CHUNK 1024
#define MT 64            // rows per block in dense kernel

typedef unsigned int uint;
typedef unsigned short ushort;
typedef __attribute__((ext_vector_type(8))) short short8;
typedef __attribute__((ext_vector_type(4))) float floatx4;

__device__ __forceinline__ floatx4 mfma16(short8 a, short8 b, floatx4 c) {
    return __builtin_amdgcn_mfma_f32_16x16x32_bf16(a, b, c, 0, 0, 0);
}

// fp32 -> bf16 bits, round-nearest-even
__device__ __forceinline__ ushort f2bf(float f) {
    uint u = __float_as_uint(f);
    u += 0x7FFFu + ((u >> 16) & 1u);
    return (ushort)(u >> 16);
}

// ---------------- setup: x->bf16 + hist(dst) + W -> swizzled (hi,lo) MFMA B-fragments ----
// grid covers max(N*D/8, E) threads. cnt must be zeroed beforehand (hipMemsetAsync).
__global__ void setup_kernel(const float* __restrict__ x,
                             const int* __restrict__ dst,
                             const float* __restrict__ Wl, const float* __restrict__ Wr,
                             ushort* __restrict__ xh,
                             ushort* __restrict__ Wswhi, ushort* __restrict__ Wswlo,
                             int* __restrict__ cnt, int n_nodes, int E) {
    const int t = blockIdx.x * blockDim.x + threadIdx.x;
    // x -> bf16, 8 per thread
    const int nconv = n_nodes * (D / 8);
    if (t < nconv) {
        int base = t * 8;
        float4 a = *(const float4*)&x[base];
        float4 b = *(const float4*)&x[base + 4];
        union { ushort h[8]; uint4 v; } pk;
        pk.h[0] = f2bf(a.x); pk.h[1] = f2bf(a.y); pk.h[2] = f2bf(a.z); pk.h[3] = f2bf(a.w);
        pk.h[4] = f2bf(b.x); pk.h[5] = f2bf(b.y); pk.h[6] = f2bf(b.z); pk.h[7] = f2bf(b.w);
        *(uint4*)&xh[base] = pk.v;
    }
    // histogram of dst
    if (t < E) atomicAdd(&cnt[dst[t]], 1);
    // W swizzle: thread -> (tile tt, step s, lane); writes 8 contiguous bf16 (hi & lo)
    if (t < 8 * 8 * 64) {
        int tt = t >> 9;            // tile (output col group), 0..7
        int rem = t & 511;
        int s  = rem >> 6;          // k-step, 0..7
        int lane = rem & 63;
        int lc = lane & 15, lq = lane >> 4;
        int col = tt * 16 + lc;     // output feature j
        int k0  = s * 32 + lq * 8;  // k base (0..255)
        union { ushort h[8]; uint4 v; } hi, lo;
        #pragma unroll
        for (int j = 0; j < 8; j++) {
            int k = k0 + j;
            float w = (k < 128) ? Wl[col * 128 + k] : Wr[col * 128 + (k - 128)];
            ushort h = f2bf(w);
            hi.h[j] = h;
            lo.h[j] = f2bf(w - __uint_as_float(((uint)h) << 16));
        }
        *(uint4*)&Wswhi[t * 8] = hi.v;
        *(uint4*)&Wswlo[t * 8] = lo.v;
    }
}

// fallback-only: fp32 W transpose
__global__ void transpose_w(const float* __restrict__ Wl, const float* __restrict__ Wr,
                            float* __restrict__ WlT, float* __restrict__ WrT) {
    int t = blockIdx.x * blockDim.x + threadIdx.x;
    if (t < D * D) {
        int j = t & (D - 1);
        int k = t >> 7;
        WlT[k * D + j] = Wl[j * D + k];
        WrT[k * D + j] = Wr[j * D + k];
    }
}

// fallback-only hist
__global__ void hist_kernel(const int* __restrict__ dst, int* __restrict__ cnt, int E) {
    int e = blockIdx.x * blockDim.x + threadIdx.x;
    if (e < E) atomicAdd(&cnt[dst[e]], 1);
}

// ---------------- scan pass 1 ----------------
__global__ __launch_bounds__(256) void scan_partial(const int* __restrict__ cnt,
                                                    int* __restrict__ bsum, int n) {
    __shared__ int ws[4];
    const int tid = threadIdx.x;
    const int lane = tid & 63, wid = tid >> 6;
    int i0 = blockIdx.x * SCAN_CHUNK + tid * 4;
    int4 v = make_int4(0, 0, 0, 0);
    if (i0 < n) v = *(const int4*)&cnt[i0];
    int t = v.x + v.y + v.z + v.w;
    #pragma unroll
    for (int m = 32; m >= 1; m >>= 1) t += __shfl_xor(t, m);
    if (lane == 0) ws[wid] = t;
    __syncthreads();
    if (tid == 0) bsum[blockIdx.x] = ws[0] + ws[1] + ws[2] + ws[3];
}

// ---------------- scan pass 2 ----------------
__global__ __launch_bounds__(1024) void scan_base(const int* __restrict__ bsum,
                                                  int* __restrict__ bbase,
                                                  int* __restrict__ offsets,
                                                  int nb, int n) {
    __shared__ int wsums[16];
    const int tid = threadIdx.x;
    const int lane = tid & 63, wid = tid >> 6;
    int v = (tid < nb) ? bsum[tid] : 0;
    int s = v;
    #pragma unroll
    for (int off = 1; off < 64; off <<= 1) {
        int t = __shfl_up(s, off);
        if (lane >= off) s += t;
    }
    if (lane == 63) wsums[wid] = s;
    __syncthreads();
    if (tid < 16) {
        int w = wsums[tid];
        #pragma unroll
        for (int off = 1; off < 16; off <<= 1) {
            int t = __shfl_up(w, off);
            if (tid >= off) w += t;
        }
        wsums[tid] = w;
    }
    __syncthreads();
    int wprefix = (wid > 0) ? wsums[wid - 1] : 0;
    if (tid < nb) bbase[tid] = wprefix + (s - v);
    if (tid == 0) offsets[n] = wsums[15];
}

// ---------------- scan pass 3 (+cursor dual-write) ----------------
__global__ __launch_bounds__(256) void scan_final(const int* __restrict__ cnt,
                                                  const int* __restrict__ bbase,
                                                  int* __restrict__ offsets,
                                                  int* __restrict__ cursor, int n) {
    __shared__ int ws[4];
    __shared__ int wpre[4];
    const int tid = threadIdx.x;
    const int lane = tid & 63, wid = tid >> 6;
    int i0 = blockIdx.x * SCAN_CHUNK + tid * 4;
    int4 v = make_int4(0, 0, 0, 0);
    if (i0 < n) v = *(const int4*)&cnt[i0];
    int tsum = v.x + v.y + v.z + v.w;
    int s = tsum;
    #pragma unroll
    for (int off = 1; off < 64; off <<= 1) {
        int t = __shfl_up(s, off);
        if (lane >= off) s += t;
    }
    if (lane == 63) ws[wid] = s;
    __syncthreads();
    if (tid == 0) {
        int a = 0;
        #pragma unroll
        for (int i = 0; i < 4; i++) { wpre[i] = a; a += ws[i]; }
    }
    __syncthreads();
    if (i0 < n) {
        int excl = bbase[blockIdx.x] + wpre[wid] + (s - tsum);
        int4 o;
        o.x = excl;
        o.y = o.x + v.x;
        o.z = o.y + v.y;
        o.w = o.z + v.z;
        *(int4*)&offsets[i0] = o;
        *(int4*)&cursor[i0]  = o;
    }
}

// ---------------- fill CSR buckets (nontemporal scattered store) ----------------
__global__ void fill_kernel(const int* __restrict__ src, const int* __restrict__ dst,
                            int* __restrict__ cursor, int* __restrict__ bucket, int E) {
    int e = blockIdx.x * blockDim.x + threadIdx.x;
    if (e < E) {
        int pos = atomicAdd(&cursor[dst[e]], 1);
        __builtin_nontemporal_store(src[e], &bucket[pos]);
    }
}

// ---------------- gather+mean: one wave per node; 16 lanes x uint4 per edge row ------
__global__ __launch_bounds__(256) void agg_kernel(
        const uint4* __restrict__ xu4,        // xh as uint4[N][16]
        const int* __restrict__ offsets, const int* __restrict__ bucket,
        uint4* __restrict__ aggu4, int n_nodes) {
    const int wave = threadIdx.x >> 6, lane = threadIdx.x & 63;
    const int g = lane >> 4;          // edge slot within quad, 0..3
    const int sub = lane & 15;        // uint4 index within row
    const int node = blockIdx.x * 4 + wave;
    if (node >= n_nodes) return;
    const int o0 = offsets[node], o1 = offsets[node + 1];
    float s[8] = {0.f, 0.f, 0.f, 0.f, 0.f, 0.f, 0.f, 0.f};

    #define ACC(v)                                             \
        { s[0] += __uint_as_float((v).x << 16);                \
          s[1] += __uint_as_float((v).x & 0xFFFF0000u);        \
          s[2] += __uint_as_float((v).y << 16);                \
          s[3] += __uint_as_float((v).y & 0xFFFF0000u);        \
          s[4] += __uint_as_float((v).z << 16);                \
          s[5] += __uint_as_float((v).z & 0xFFFF0000u);        \
          s[6] += __uint_as_float((v).w << 16);                \
          s[7] += __uint_as_float((v).w & 0xFFFF0000u); }

    int e = o0;
    for (; e + 16 <= o1; e += 16) {
        int i0 = bucket[e + g], i1 = bucket[e + 4 + g];
        int i2 = bucket[e + 8 + g], i3 = bucket[e + 12 + g];
        uint4 a = xu4[(size_t)i0 * 16 + sub];
        uint4 b = xu4[(size_t)i1 * 16 + sub];
        uint4 c = xu4[(size_t)i2 * 16 + sub];
        uint4 d = xu4[(size_t)i3 * 16 + sub];
        ACC(a) ACC(b) ACC(c) ACC(d)
    }
    for (; e < o1; e += 4) {
        int ee = e + g;
        if (ee < o1) {
            uint4 a = xu4[(size_t)bucket[ee] * 16 + sub];
            ACC(a)
        }
    }
    #undef ACC

    // reduce across the 4 edge-slots (lanes sub, sub+16, sub+32, sub+48)
    #pragma unroll
    for (int m = 16; m <= 32; m <<= 1)
        #pragma unroll
        for (int j = 0; j < 8; j++) s[j] += __shfl_xor(s[j], m);

    if (g == 0) {
        int deg = o1 - o0;
        float inv = 1.f / (float)(deg > 0 ? deg : 1);
        uint4 o;
        o.x = (uint)f2bf(s[0] * inv) | (((uint)f2bf(s[1] * inv)) << 16);
        o.y = (uint)f2bf(s[2] * inv) | (((uint)f2bf(s[3] * inv)) << 16);
        o.z = (uint)f2bf(s[4] * inv) | (((uint)f2bf(s[5] * inv)) << 16);
        o.w = (uint)f2bf(s[6] * inv) | (((uint)f2bf(s[7] * inv)) << 16);
        aggu4[(size_t)node * 16 + sub] = o;
    }
}

// ---------------- dense: MFMA GEMM [agg|x]·Wcat^T + bias + GELU + LN + residual ------
// No LDS; W read from pre-swizzled fragments (L1/L2-hot). One wave = 16 rows.
__global__ __launch_bounds__(256) void dense_kernel(
        const ushort* __restrict__ aggh, const ushort* __restrict__ xh,
        const ushort* __restrict__ Wswhi, const ushort* __restrict__ Wswlo,
        const float* __restrict__ bl, const float* __restrict__ gam,
        const float* __restrict__ bet,
        float* __restrict__ out, int n_nodes) {
    const int tid = threadIdx.x, wave = tid >> 6, lane = tid & 63;
    const int lc = lane & 15, lq = lane >> 4;
    const int m0 = blockIdx.x * MT + wave * 16;

    floatx4 acc[8];
    #pragma unroll
    for (int t = 0; t < 8; t++) acc[t] = (floatx4){0.f, 0.f, 0.f, 0.f};

    int arow = m0 + lc;
    if (arow >= n_nodes) arow = n_nodes - 1;
    const int ko = lq * 8;

    #pragma unroll
    for (int s = 0; s < 8; s++) {       // K=256: s<4 agg half, s>=4 x half
        const ushort* ap = (s < 4)
            ? (aggh + (size_t)arow * D + s * 32 + ko)
            : (xh   + (size_t)arow * D + (s - 4) * 32 + ko);
        short8 av = *(const short8*)ap;
        #pragma unroll
        for (int t = 0; t < 8; t++) {
            short8 bh = *(const short8*)&Wswhi[((t * 8 + s) * 64 + lane) * 8];
            acc[t] = mfma16(av, bh, acc[t]);
        }
        #pragma unroll
        for (int t = 0; t < 8; t++) {
            short8 bo = *(const short8*)&Wswlo[((t * 8 + s) * 64 + lane) * 8];
            acc[t] = mfma16(av, bo, acc[t]);
        }
    }

    // epilogue: bias + GELU + LN (C layout: row = m0 + lq*4 + r, col = t*16 + lc)
    float psum[4] = {0.f, 0.f, 0.f, 0.f};
    float psq[4]  = {0.f, 0.f, 0.f, 0.f};
    #pragma unroll
    for (int t = 0; t < 8; t++) {
        float bb = bl[t * 16 + lc];
        #pragma unroll
        for (int r = 0; r < 4; r++) {
            float f = acc[t][r] + bb;
            float g = 0.5f * f * (1.f + erff(f * 0.70710678118654752440f));
            acc[t][r] = g;
            psum[r] += g;
            psq[r]  += g * g;
        }
    }
    #pragma unroll
    for (int m = 8; m >= 1; m >>= 1) {
        #pragma unroll
        for (int r = 0; r < 4; r++) {
            psum[r] += __shfl_xor(psum[r], m);
            psq[r]  += __shfl_xor(psq[r], m);
        }
    }
    float mu[4], rs[4];
    #pragma unroll
    for (int r = 0; r < 4; r++) {
        mu[r] = psum[r] * (1.f / (float)D);
        float var = psq[r] * (1.f / (float)D) - mu[r] * mu[r];
        rs[r] = rsqrtf(var + LN_EPS);
    }
    #pragma unroll
    for (int t = 0; t < 8; t++) {
        int col = t * 16 + lc;
        float gm = gam[col], bt = bet[col];
        #pragma unroll
        for (int r = 0; r < 4; r++) {
            int row = m0 + lq * 4 + r;
            if (row < n_nodes) {
                float xr = __uint_as_float(((uint)xh[(size_t)row * D + col]) << 16);
                out[(size_t)row * D + col] = (acc[t][r] - mu[r]) * rs[r] * gm + bt + xr;
            }
        }
    }
}

// ---------------- fallback fused fp32 (proven R2 path) ----------------
#define NBF 32
#define LSTR 132
__global__ __launch_bounds__(256, 4) void fused_fb(
        const float* __restrict__ x,
        const float* __restrict__ WlT, const float* __restrict__ WrT,
        const float* __restrict__ bl,  const float* __restrict__ gam,
        const float* __restrict__ bet,
        const int* __restrict__ offsets, const int* __restrict__ bucket,
        float* __restrict__ out, int n_nodes) {
    __shared__ __align__(16) float sagg[NBF * LSTR];
    __shared__ __align__(16) float sx[NBF * LSTR];
    const int tid   = threadIdx.x;
    const int node0 = blockIdx.x * NBF;
    const int hl = tid & 31, hw = tid >> 5, hl4 = hl * 4;
    #pragma unroll
    for (int r = 0; r < NBF / 8; r++) {
        const int n = r * 8 + hw;
        const int g = node0 + n;
        float s0 = 0.f, s1 = 0.f, s2 = 0.f, s3 = 0.f;
        float4 xv = make_float4(0.f, 0.f, 0.f, 0.f);
        float inv = 0.f;
        if (g < n_nodes) {
            const int o0 = offsets[g], o1 = offsets[g + 1];
            int e = o0;
            for (; e + 4 <= o1; e += 4) {
                int i0 = bucket[e], i1 = bucket[e + 1], i2 = bucket[e + 2], i3 = bucket[e + 3];
                float4 a0 = *(const float4*)&x[i0 * D + hl4];
                float4 a1 = *(const float4*)&x[i1 * D + hl4];
                float4 a2 = *(const float4*)&x[i2 * D + hl4];
                float4 a3 = *(const float4*)&x[i3 * D + hl4];
                s0 += (a0.x + a1.x) + (a2.x + a3.x);
                s1 += (a0.y + a1.y) + (a2.y + a3.y);
                s2 += (a0.z + a1.z) + (a2.z + a3.z);
                s3 += (a0.w + a1.w) + (a2.w + a3.w);
            }
            for (; e < o1; e++) {
                float4 a = *(const float4*)&x[bucket[e] * D + hl4];
                s0 += a.x; s1 += a.y; s2 += a.z; s3 += a.w;
            }
            int deg = o1 - o0;
            inv = 1.f / (float)(deg > 0 ? deg : 1);
            xv = *(const float4*)&x[g * D + hl4];
        }
        *(float4*)&sagg[n * LSTR + hl4] = make_float4(s0 * inv, s1 * inv, s2 * inv, s3 * inv);
        *(float4*)&sx[n * LSTR + hl4]   = xv;
    }
    __syncthreads();
    const int tj = tid & 31, tn = tid >> 5;
    const int j0 = tj * 4, n0 = tn * 4;
    float4 blv = *(const float4*)&bl[j0];
    float acc[4][4];
    #pragma unroll
    for (int nn = 0; nn < 4; nn++) {
        acc[0][nn] = blv.x; acc[1][nn] = blv.y; acc[2][nn] = blv.z; acc[3][nn] = blv.w;
    }
    for (int kc = 0; kc < D; kc += 4) {
        float4 av[4], bv[4];
        #pragma unroll
        for (int nn = 0; nn < 4; nn++) {
            av[nn] = *(const float4*)&sagg[(n0 + nn) * LSTR + kc];
            bv[nn] = *(const float4*)&sx[(n0 + nn) * LSTR + kc];
        }
        #pragma unroll
        for (int kk = 0; kk < 4; kk++) {
            float4 wl = *(const float4*)&WlT[(kc + kk) * D + j0];
            float4 wr = *(const float4*)&WrT[(kc + kk) * D + j0];
            float wlv[4] = {wl.x, wl.y, wl.z, wl.w};
            float wrv[4] = {wr.x, wr.y, wr.z, wr.w};
            #pragma unroll
            for (int nn = 0; nn < 4; nn++) {
                float a = ((const float*)&av[nn])[kk];
                float b = ((const float*)&bv[nn])[kk];
                #pragma unroll
                for (int jj = 0; jj < 4; jj++)
                    acc[jj][nn] = fmaf(wlv[jj], a, fmaf(wrv[jj], b, acc[jj][nn]));
            }
        }
    }
    float psum[4] = {0.f, 0.f, 0.f, 0.f};
    float psq[4]  = {0.f, 0.f, 0.f, 0.f};
    #pragma unroll
    for (int jj = 0; jj < 4; jj++)
        #pragma unroll
        for (int nn = 0; nn < 4; nn++) {
            float f = acc[jj][nn];
            float g = 0.5f * f * (1.f + erff(f * 0.70710678118654752440f));
            acc[jj][nn] = g;
            psum[nn] += g;
            psq[nn]  += g * g;
        }
    #pragma unroll
    for (int m = 16; m >= 1; m >>= 1) {
        #pragma unroll
        for (int nn = 0; nn < 4; nn++) {
            psum[nn] += __shfl_xor(psum[nn], m);
            psq[nn]  += __shfl_xor(psq[nn], m);
        }
    }
    float4 gv = *(const float4*)&gam[j0];
    float4 bv4 = *(const float4*)&bet[j0];
    float gvv[4] = {gv.x, gv.y, gv.z, gv.w};
    float bvv[4] = {bv4.x, bv4.y, bv4.z, bv4.w};
    #pragma unroll
    for (int nn = 0; nn < 4; nn++) {
        int node = node0 + n0 + nn;
        if (node < n_nodes) {
            float m2  = psum[nn] * (1.f / (float)D);
            float var = psq[nn] * (1.f / (float)D) - m2 * m2;
            float rs  = rsqrtf(var + LN_EPS);
            float4 xr = *(const float4*)&x[node * D + j0];
            float xrv[4] = {xr.x, xr.y, xr.z, xr.w};
            float o[4];
            #pragma unroll
            for (int jj = 0; jj < 4; jj++)
                o[jj] = (acc[jj][nn] - m2) * rs * gvv[jj] + bvv[jj] + xrv[jj];
            *(float4*)&out[node * D + j0] = make_float4(o[0], o[1], o[2], o[3]);
        }
    }
}

static inline size_t align_up(size_t v, size_t a) { return (v + a - 1) & ~(a - 1); }

extern "C" void kernel_launch(void* const* d_in, const int* in_sizes, int n_in,
                              void* d_out, int out_size, void* d_ws, size_t ws_size,
                              hipStream_t stream) {
    const float* x   = (const float*)d_in[0];
    const int*   ei  = (const int*)d_in[1];
    const float* Wl  = (const float*)d_in[2];
    const float* bl  = (const float*)d_in[3];
    const float* Wr  = (const float*)d_in[4];
    const float* gam = (const float*)d_in[5];
    const float* bet = (const float*)d_in[6];
    float* out = (float*)d_out;

    const int N = in_sizes[0] / D;
    const int E = in_sizes[1] / 2;
    const int* src = ei;
    const int* dst = ei + E;
    const int nblk = (N + SCAN_CHUNK - 1) / SCAN_CHUNK;

    // workspace carve
    char* p = (char*)d_ws;
    int* cnt    = (int*)p;            // N
    int* cursor = cnt + N;            // N
    p = (char*)align_up((size_t)(cursor + N), 256);
    int* offsets = (int*)p;           // N+1
    p = (char*)align_up((size_t)(offsets + N + 1), 256);
    int* bucket = (int*)p;            // E
    p = (char*)align_up((size_t)(bucket + E), 256);
    ushort* Wswhi = (ushort*)p;       // 32768 (64 KB)   [fallback overlays WlT/WrT here]
    ushort* Wswlo = Wswhi + 32768;    // 64 KB
    float* WlT = (float*)Wswhi;
    float* WrT = WlT + D * D;
    p = (char*)align_up((size_t)(Wswlo + 32768), 256);
    int* bsum  = (int*)p;
    int* bbase = bsum + 1024;
    p = (char*)align_up((size_t)(bbase + 1024), 256);
    ushort* xh   = (ushort*)p;        // N*128 bf16 (25.6 MB)
    ushort* aggh = xh + (size_t)N * D;// N*128 bf16 (25.6 MB)
    size_t need_full = (size_t)((char*)(aggh + (size_t)N * D) - (char*)d_ws);
    const bool full = (ws_size >= need_full);

    if (full) {
        hipMemsetAsync(cnt, 0, (size_t)N * sizeof(int), stream);
        const int setup_threads = (N * (D / 8) > E) ? N * (D / 8) : E;
        setup_kernel<<<(setup_threads + 255) / 256, 256, 0, stream>>>(
            x, dst, Wl, Wr, xh, Wswhi, Wswlo, cnt, N, E);
        scan_partial<<<nblk, 256, 0, stream>>>(cnt, bsum, N);
        scan_base<<<1, 1024, 0, stream>>>(bsum, bbase, offsets, nblk, N);
        scan_final<<<nblk, 256, 0, stream>>>(cnt, bbase, offsets, cursor, N);
        fill_kernel<<<(E + 255) / 256, 256, 0, stream>>>(src, dst, cursor, bucket, E);
        agg_kernel<<<(N + 3) / 4, 256, 0, stream>>>(
            (const uint4*)xh, offsets, bucket, (uint4*)aggh, N);
        dense_kernel<<<(N + MT - 1) / MT, 256, 0, stream>>>(
            aggh, xh, Wswhi, Wswlo, bl, gam, bet, out, N);
    } else {
        // fallback: proven fp32 fused path (small ws)
        hipMemsetAsync(cnt, 0, (size_t)N * sizeof(int), stream);
        transpose_w<<<(D * D + 255) / 256, 256, 0, stream>>>(Wl, Wr, WlT, WrT);
        hist_kernel<<<(E + 255) / 256, 256, 0, stream>>>(dst, cnt, E);
        scan_partial<<<nblk, 256, 0, stream>>>(cnt, bsum, N);
        scan_base<<<1, 1024, 0, stream>>>(bsum, bbase, offsets, nblk, N);
        scan_final<<<nblk, 256, 0, stream>>>(cnt, bbase, offsets, cursor, N);
        fill_kernel<<<(E + 255) / 256, 256, 0, stream>>>(src, dst, cursor, bucket, E);
        fused_fb<<<(N + NBF - 1) / NBF, 256, 0, stream>>>(
            x, WlT, WrT, bl, gam, bet, offsets, bucket, out, N);
    }
}

// Round 6
// 375.468 us; speedup vs baseline: 1.3298x; 1.1418x over previous
//
#include <hip/hip_runtime.h>
#include <math.h>

#define D 128
#define LN_EPS 1e-5f
#define SCAN_CHUNK 1024
#define MT 64            // rows per block in dense kernel

typedef unsigned int uint;
typedef unsigned short ushort;
typedef __attribute__((ext_vector_type(8))) short short8;
typedef __attribute__((ext_vector_type(4))) float floatx4;

__device__ __forceinline__ floatx4 mfma16(short8 a, short8 b, floatx4 c) {
    return __builtin_amdgcn_mfma_f32_16x16x32_bf16(a, b, c, 0, 0, 0);
}

// fp32 -> bf16 bits, round-nearest-even
__device__ __forceinline__ ushort f2bf(float f) {
    uint u = __float_as_uint(f);
    u += 0x7FFFu + ((u >> 16) & 1u);
    return (ushort)(u >> 16);
}

// ---------------- setup: x->bf16 + hist(dst) + W -> swizzled (hi,lo) MFMA B-fragments ----
__global__ void setup_kernel(const float* __restrict__ x,
                             const int* __restrict__ dst,
                             const float* __restrict__ Wl, const float* __restrict__ Wr,
                             ushort* __restrict__ xh,
                             ushort* __restrict__ Wswhi, ushort* __restrict__ Wswlo,
                             int* __restrict__ cnt, int n_nodes, int E) {
    const int t = blockIdx.x * blockDim.x + threadIdx.x;
    const int nconv = n_nodes * (D / 8);
    if (t < nconv) {
        int base = t * 8;
        float4 a = *(const float4*)&x[base];
        float4 b = *(const float4*)&x[base + 4];
        union { ushort h[8]; uint4 v; } pk;
        pk.h[0] = f2bf(a.x); pk.h[1] = f2bf(a.y); pk.h[2] = f2bf(a.z); pk.h[3] = f2bf(a.w);
        pk.h[4] = f2bf(b.x); pk.h[5] = f2bf(b.y); pk.h[6] = f2bf(b.z); pk.h[7] = f2bf(b.w);
        *(uint4*)&xh[base] = pk.v;
    }
    if (t < E) atomicAdd(&cnt[dst[t]], 1);
    // W swizzle: thread -> (tile tt, step s, lane); writes 8 contiguous bf16 (hi & lo)
    if (t < 8 * 8 * 64) {
        int tt = t >> 9;
        int rem = t & 511;
        int s  = rem >> 6;
        int lane = rem & 63;
        int lc = lane & 15, lq = lane >> 4;
        int col = tt * 16 + lc;
        int k0  = s * 32 + lq * 8;
        union { ushort h[8]; uint4 v; } hi, lo;
        #pragma unroll
        for (int j = 0; j < 8; j++) {
            int k = k0 + j;
            float w = (k < 128) ? Wl[col * 128 + k] : Wr[col * 128 + (k - 128)];
            ushort h = f2bf(w);
            hi.h[j] = h;
            lo.h[j] = f2bf(w - __uint_as_float(((uint)h) << 16));
        }
        *(uint4*)&Wswhi[t * 8] = hi.v;
        *(uint4*)&Wswlo[t * 8] = lo.v;
    }
}

// fallback-only: fp32 W transpose
__global__ void transpose_w(const float* __restrict__ Wl, const float* __restrict__ Wr,
                            float* __restrict__ WlT, float* __restrict__ WrT) {
    int t = blockIdx.x * blockDim.x + threadIdx.x;
    if (t < D * D) {
        int j = t & (D - 1);
        int k = t >> 7;
        WlT[k * D + j] = Wl[j * D + k];
        WrT[k * D + j] = Wr[j * D + k];
    }
}

// fallback-only hist
__global__ void hist_kernel(const int* __restrict__ dst, int* __restrict__ cnt, int E) {
    int e = blockIdx.x * blockDim.x + threadIdx.x;
    if (e < E) atomicAdd(&cnt[dst[e]], 1);
}

// ---------------- scan pass 1 ----------------
__global__ __launch_bounds__(256) void scan_partial(const int* __restrict__ cnt,
                                                    int* __restrict__ bsum, int n) {
    __shared__ int ws[4];
    const int tid = threadIdx.x;
    const int lane = tid & 63, wid = tid >> 6;
    int i0 = blockIdx.x * SCAN_CHUNK + tid * 4;
    int4 v = make_int4(0, 0, 0, 0);
    if (i0 < n) v = *(const int4*)&cnt[i0];
    int t = v.x + v.y + v.z + v.w;
    #pragma unroll
    for (int m = 32; m >= 1; m >>= 1) t += __shfl_xor(t, m);
    if (lane == 0) ws[wid] = t;
    __syncthreads();
    if (tid == 0) bsum[blockIdx.x] = ws[0] + ws[1] + ws[2] + ws[3];
}

// ---------------- scan pass 2 ----------------
__global__ __launch_bounds__(1024) void scan_base(const int* __restrict__ bsum,
                                                  int* __restrict__ bbase,
                                                  int* __restrict__ offsets,
                                                  int nb, int n) {
    __shared__ int wsums[16];
    const int tid = threadIdx.x;
    const int lane = tid & 63, wid = tid >> 6;
    int v = (tid < nb) ? bsum[tid] : 0;
    int s = v;
    #pragma unroll
    for (int off = 1; off < 64; off <<= 1) {
        int t = __shfl_up(s, off);
        if (lane >= off) s += t;
    }
    if (lane == 63) wsums[wid] = s;
    __syncthreads();
    if (tid < 16) {
        int w = wsums[tid];
        #pragma unroll
        for (int off = 1; off < 16; off <<= 1) {
            int t = __shfl_up(w, off);
            if (tid >= off) w += t;
        }
        wsums[tid] = w;
    }
    __syncthreads();
    int wprefix = (wid > 0) ? wsums[wid - 1] : 0;
    if (tid < nb) bbase[tid] = wprefix + (s - v);
    if (tid == 0) offsets[n] = wsums[15];
}

// ---------------- scan pass 3 (+cursor dual-write) ----------------
__global__ __launch_bounds__(256) void scan_final(const int* __restrict__ cnt,
                                                  const int* __restrict__ bbase,
                                                  int* __restrict__ offsets,
                                                  int* __restrict__ cursor, int n) {
    __shared__ int ws[4];
    __shared__ int wpre[4];
    const int tid = threadIdx.x;
    const int lane = tid & 63, wid = tid >> 6;
    int i0 = blockIdx.x * SCAN_CHUNK + tid * 4;
    int4 v = make_int4(0, 0, 0, 0);
    if (i0 < n) v = *(const int4*)&cnt[i0];
    int tsum = v.x + v.y + v.z + v.w;
    int s = tsum;
    #pragma unroll
    for (int off = 1; off < 64; off <<= 1) {
        int t = __shfl_up(s, off);
        if (lane >= off) s += t;
    }
    if (lane == 63) ws[wid] = s;
    __syncthreads();
    if (tid == 0) {
        int a = 0;
        #pragma unroll
        for (int i = 0; i < 4; i++) { wpre[i] = a; a += ws[i]; }
    }
    __syncthreads();
    if (i0 < n) {
        int excl = bbase[blockIdx.x] + wpre[wid] + (s - tsum);
        int4 o;
        o.x = excl;
        o.y = o.x + v.x;
        o.z = o.y + v.y;
        o.w = o.z + v.z;
        *(int4*)&offsets[i0] = o;
        *(int4*)&cursor[i0]  = o;
    }
}

// ---------------- fill CSR buckets, XCD-partitioned by dst range ----------------
// blockIdx%8 ~ XCD (round-robin dispatch heuristic). Group g only handles dst in
// [g*rn, (g+1)*rn) so its cursor slice (~50 KB) and bucket slice (~800 KB) stay
// resident in ONE XCD's L2 -> the ~16 writes per 64B line merge before writeback.
// Correctness does not depend on the mapping; only locality does.
__global__ __launch_bounds__(256) void fill_kernel(
        const int* __restrict__ src, const int* __restrict__ dst,
        int* __restrict__ cursor, int* __restrict__ bucket, int E, int rn) {
    const int g   = blockIdx.x & 7;           // dst-range group (~XCD)
    const int cid = blockIdx.x >> 3;          // chunk within group, 0..255
    const int lo = g * rn, hi = lo + rn;
    for (int e = cid * 256 + threadIdx.x; e < E; e += 65536) {
        int d = dst[e];
        if (d >= lo && d < hi) {
            int pos = atomicAdd(&cursor[d], 1);
            bucket[pos] = src[e];
        }
    }
}

// ---------------- gather+mean: one wave per node; 16 lanes x uint4 per edge row ------
__global__ __launch_bounds__(256) void agg_kernel(
        const uint4* __restrict__ xu4,        // xh as uint4[N][16]
        const int* __restrict__ offsets, const int* __restrict__ bucket,
        uint4* __restrict__ aggu4, int n_nodes) {
    const int wave = threadIdx.x >> 6, lane = threadIdx.x & 63;
    const int g = lane >> 4;          // edge slot within quad, 0..3
    const int sub = lane & 15;        // uint4 index within row
    const int node = blockIdx.x * 4 + wave;
    if (node >= n_nodes) return;
    const int o0 = offsets[node], o1 = offsets[node + 1];
    float s[8] = {0.f, 0.f, 0.f, 0.f, 0.f, 0.f, 0.f, 0.f};

    #define ACC(v)                                             \
        { s[0] += __uint_as_float((v).x << 16);                \
          s[1] += __uint_as_float((v).x & 0xFFFF0000u);        \
          s[2] += __uint_as_float((v).y << 16);                \
          s[3] += __uint_as_float((v).y & 0xFFFF0000u);        \
          s[4] += __uint_as_float((v).z << 16);                \
          s[5] += __uint_as_float((v).z & 0xFFFF0000u);        \
          s[6] += __uint_as_float((v).w << 16);                \
          s[7] += __uint_as_float((v).w & 0xFFFF0000u); }

    int e = o0;
    for (; e + 16 <= o1; e += 16) {
        int i0 = bucket[e + g], i1 = bucket[e + 4 + g];
        int i2 = bucket[e + 8 + g], i3 = bucket[e + 12 + g];
        uint4 a = xu4[(size_t)i0 * 16 + sub];
        uint4 b = xu4[(size_t)i1 * 16 + sub];
        uint4 c = xu4[(size_t)i2 * 16 + sub];
        uint4 d = xu4[(size_t)i3 * 16 + sub];
        ACC(a) ACC(b) ACC(c) ACC(d)
    }
    for (; e < o1; e += 4) {
        int ee = e + g;
        if (ee < o1) {
            uint4 a = xu4[(size_t)bucket[ee] * 16 + sub];
            ACC(a)
        }
    }
    #undef ACC

    #pragma unroll
    for (int m = 16; m <= 32; m <<= 1)
        #pragma unroll
        for (int j = 0; j < 8; j++) s[j] += __shfl_xor(s[j], m);

    if (g == 0) {
        int deg = o1 - o0;
        float inv = 1.f / (float)(deg > 0 ? deg : 1);
        uint4 o;
        o.x = (uint)f2bf(s[0] * inv) | (((uint)f2bf(s[1] * inv)) << 16);
        o.y = (uint)f2bf(s[2] * inv) | (((uint)f2bf(s[3] * inv)) << 16);
        o.z = (uint)f2bf(s[4] * inv) | (((uint)f2bf(s[5] * inv)) << 16);
        o.w = (uint)f2bf(s[6] * inv) | (((uint)f2bf(s[7] * inv)) << 16);
        aggu4[(size_t)node * 16 + sub] = o;
    }
}

// ---------------- dense: MFMA GEMM [agg|x]·Wcat^T + bias + GELU + LN + residual ------
__global__ __launch_bounds__(256) void dense_kernel(
        const ushort* __restrict__ aggh, const ushort* __restrict__ xh,
        const ushort* __restrict__ Wswhi, const ushort* __restrict__ Wswlo,
        const float* __restrict__ bl, const float* __restrict__ gam,
        const float* __restrict__ bet,
        float* __restrict__ out, int n_nodes) {
    const int tid = threadIdx.x, wave = tid >> 6, lane = tid & 63;
    const int lc = lane & 15, lq = lane >> 4;
    const int m0 = blockIdx.x * MT + wave * 16;

    floatx4 acc[8];
    #pragma unroll
    for (int t = 0; t < 8; t++) acc[t] = (floatx4){0.f, 0.f, 0.f, 0.f};

    int arow = m0 + lc;
    if (arow >= n_nodes) arow = n_nodes - 1;
    const int ko = lq * 8;

    #pragma unroll
    for (int s = 0; s < 8; s++) {       // K=256: s<4 agg half, s>=4 x half
        const ushort* ap = (s < 4)
            ? (aggh + (size_t)arow * D + s * 32 + ko)
            : (xh   + (size_t)arow * D + (s - 4) * 32 + ko);
        short8 av = *(const short8*)ap;
        #pragma unroll
        for (int t = 0; t < 8; t++) {
            short8 bh = *(const short8*)&Wswhi[((t * 8 + s) * 64 + lane) * 8];
            acc[t] = mfma16(av, bh, acc[t]);
        }
        #pragma unroll
        for (int t = 0; t < 8; t++) {
            short8 bo = *(const short8*)&Wswlo[((t * 8 + s) * 64 + lane) * 8];
            acc[t] = mfma16(av, bo, acc[t]);
        }
    }

    float psum[4] = {0.f, 0.f, 0.f, 0.f};
    float psq[4]  = {0.f, 0.f, 0.f, 0.f};
    #pragma unroll
    for (int t = 0; t < 8; t++) {
        float bb = bl[t * 16 + lc];
        #pragma unroll
        for (int r = 0; r < 4; r++) {
            float f = acc[t][r] + bb;
            float g = 0.5f * f * (1.f + erff(f * 0.70710678118654752440f));
            acc[t][r] = g;
            psum[r] += g;
            psq[r]  += g * g;
        }
    }
    #pragma unroll
    for (int m = 8; m >= 1; m >>= 1) {
        #pragma unroll
        for (int r = 0; r < 4; r++) {
            psum[r] += __shfl_xor(psum[r], m);
            psq[r]  += __shfl_xor(psq[r], m);
        }
    }
    float mu[4], rs[4];
    #pragma unroll
    for (int r = 0; r < 4; r++) {
        mu[r] = psum[r] * (1.f / (float)D);
        float var = psq[r] * (1.f / (float)D) - mu[r] * mu[r];
        rs[r] = rsqrtf(var + LN_EPS);
    }
    #pragma unroll
    for (int t = 0; t < 8; t++) {
        int col = t * 16 + lc;
        float gm = gam[col], bt = bet[col];
        #pragma unroll
        for (int r = 0; r < 4; r++) {
            int row = m0 + lq * 4 + r;
            if (row < n_nodes) {
                float xr = __uint_as_float(((uint)xh[(size_t)row * D + col]) << 16);
                out[(size_t)row * D + col] = (acc[t][r] - mu[r]) * rs[r] * gm + bt + xr;
            }
        }
    }
}

// ---------------- fallback fused fp32 (proven R2 path) ----------------
#define NBF 32
#define LSTR 132
__global__ __launch_bounds__(256, 4) void fused_fb(
        const float* __restrict__ x,
        const float* __restrict__ WlT, const float* __restrict__ WrT,
        const float* __restrict__ bl,  const float* __restrict__ gam,
        const float* __restrict__ bet,
        const int* __restrict__ offsets, const int* __restrict__ bucket,
        float* __restrict__ out, int n_nodes) {
    __shared__ __align__(16) float sagg[NBF * LSTR];
    __shared__ __align__(16) float sx[NBF * LSTR];
    const int tid   = threadIdx.x;
    const int node0 = blockIdx.x * NBF;
    const int hl = tid & 31, hw = tid >> 5, hl4 = hl * 4;
    #pragma unroll
    for (int r = 0; r < NBF / 8; r++) {
        const int n = r * 8 + hw;
        const int g = node0 + n;
        float s0 = 0.f, s1 = 0.f, s2 = 0.f, s3 = 0.f;
        float4 xv = make_float4(0.f, 0.f, 0.f, 0.f);
        float inv = 0.f;
        if (g < n_nodes) {
            const int o0 = offsets[g], o1 = offsets[g + 1];
            int e = o0;
            for (; e + 4 <= o1; e += 4) {
                int i0 = bucket[e], i1 = bucket[e + 1], i2 = bucket[e + 2], i3 = bucket[e + 3];
                float4 a0 = *(const float4*)&x[i0 * D + hl4];
                float4 a1 = *(const float4*)&x[i1 * D + hl4];
                float4 a2 = *(const float4*)&x[i2 * D + hl4];
                float4 a3 = *(const float4*)&x[i3 * D + hl4];
                s0 += (a0.x + a1.x) + (a2.x + a3.x);
                s1 += (a0.y + a1.y) + (a2.y + a3.y);
                s2 += (a0.z + a1.z) + (a2.z + a3.z);
                s3 += (a0.w + a1.w) + (a2.w + a3.w);
            }
            for (; e < o1; e++) {
                float4 a = *(const float4*)&x[bucket[e] * D + hl4];
                s0 += a.x; s1 += a.y; s2 += a.z; s3 += a.w;
            }
            int deg = o1 - o0;
            inv = 1.f / (float)(deg > 0 ? deg : 1);
            xv = *(const float4*)&x[g * D + hl4];
        }
        *(float4*)&sagg[n * LSTR + hl4] = make_float4(s0 * inv, s1 * inv, s2 * inv, s3 * inv);
        *(float4*)&sx[n * LSTR + hl4]   = xv;
    }
    __syncthreads();
    const int tj = tid & 31, tn = tid >> 5;
    const int j0 = tj * 4, n0 = tn * 4;
    float4 blv = *(const float4*)&bl[j0];
    float acc[4][4];
    #pragma unroll
    for (int nn = 0; nn < 4; nn++) {
        acc[0][nn] = blv.x; acc[1][nn] = blv.y; acc[2][nn] = blv.z; acc[3][nn] = blv.w;
    }
    for (int kc = 0; kc < D; kc += 4) {
        float4 av[4], bv[4];
        #pragma unroll
        for (int nn = 0; nn < 4; nn++) {
            av[nn] = *(const float4*)&sagg[(n0 + nn) * LSTR + kc];
            bv[nn] = *(const float4*)&sx[(n0 + nn) * LSTR + kc];
        }
        #pragma unroll
        for (int kk = 0; kk < 4; kk++) {
            float4 wl = *(const float4*)&WlT[(kc + kk) * D + j0];
            float4 wr = *(const float4*)&WrT[(kc + kk) * D + j0];
            float wlv[4] = {wl.x, wl.y, wl.z, wl.w};
            float wrv[4] = {wr.x, wr.y, wr.z, wr.w};
            #pragma unroll
            for (int nn = 0; nn < 4; nn++) {
                float a = ((const float*)&av[nn])[kk];
                float b = ((const float*)&bv[nn])[kk];
                #pragma unroll
                for (int jj = 0; jj < 4; jj++)
                    acc[jj][nn] = fmaf(wlv[jj], a, fmaf(wrv[jj], b, acc[jj][nn]));
            }
        }
    }
    float psum[4] = {0.f, 0.f, 0.f, 0.f};
    float psq[4]  = {0.f, 0.f, 0.f, 0.f};
    #pragma unroll
    for (int jj = 0; jj < 4; jj++)
        #pragma unroll
        for (int nn = 0; nn < 4; nn++) {
            float f = acc[jj][nn];
            float g = 0.5f * f * (1.f + erff(f * 0.70710678118654752440f));
            acc[jj][nn] = g;
            psum[nn] += g;
            psq[nn]  += g * g;
        }
    #pragma unroll
    for (int m = 16; m >= 1; m >>= 1) {
        #pragma unroll
        for (int nn = 0; nn < 4; nn++) {
            psum[nn] += __shfl_xor(psum[nn], m);
            psq[nn]  += __shfl_xor(psq[nn], m);
        }
    }
    float4 gv = *(const float4*)&gam[j0];
    float4 bv4 = *(const float4*)&bet[j0];
    float gvv[4] = {gv.x, gv.y, gv.z, gv.w};
    float bvv[4] = {bv4.x, bv4.y, bv4.z, bv4.w};
    #pragma unroll
    for (int nn = 0; nn < 4; nn++) {
        int node = node0 + n0 + nn;
        if (node < n_nodes) {
            float m2  = psum[nn] * (1.f / (float)D);
            float var = psq[nn] * (1.f / (float)D) - m2 * m2;
            float rs  = rsqrtf(var + LN_EPS);
            float4 xr = *(const float4*)&x[node * D + j0];
            float xrv[4] = {xr.x, xr.y, xr.z, xr.w};
            float o[4];
            #pragma unroll
            for (int jj = 0; jj < 4; jj++)
                o[jj] = (acc[jj][nn] - m2) * rs * gvv[jj] + bvv[jj] + xrv[jj];
            *(float4*)&out[node * D + j0] = make_float4(o[0], o[1], o[2], o[3]);
        }
    }
}

static inline size_t align_up(size_t v, size_t a) { return (v + a - 1) & ~(a - 1); }

extern "C" void kernel_launch(void* const* d_in, const int* in_sizes, int n_in,
                              void* d_out, int out_size, void* d_ws, size_t ws_size,
                              hipStream_t stream) {
    const float* x   = (const float*)d_in[0];
    const int*   ei  = (const int*)d_in[1];
    const float* Wl  = (const float*)d_in[2];
    const float* bl  = (const float*)d_in[3];
    const float* Wr  = (const float*)d_in[4];
    const float* gam = (const float*)d_in[5];
    const float* bet = (const float*)d_in[6];
    float* out = (float*)d_out;

    const int N = in_sizes[0] / D;
    const int E = in_sizes[1] / 2;
    const int* src = ei;
    const int* dst = ei + E;
    const int nblk = (N + SCAN_CHUNK - 1) / SCAN_CHUNK;
    const int rn = (N + 7) / 8;    // dst-range size per XCD group

    // workspace carve
    char* p = (char*)d_ws;
    int* cnt    = (int*)p;            // N
    int* cursor = cnt + N;            // N
    p = (char*)align_up((size_t)(cursor + N), 256);
    int* offsets = (int*)p;           // N+1
    p = (char*)align_up((size_t)(offsets + N + 1), 256);
    int* bucket = (int*)p;            // E
    p = (char*)align_up((size_t)(bucket + E), 256);
    ushort* Wswhi = (ushort*)p;       // 32768 (64 KB)   [fallback overlays WlT/WrT here]
    ushort* Wswlo = Wswhi + 32768;    // 64 KB
    float* WlT = (float*)Wswhi;
    float* WrT = WlT + D * D;
    p = (char*)align_up((size_t)(Wswlo + 32768), 256);
    int* bsum  = (int*)p;
    int* bbase = bsum + 1024;
    p = (char*)align_up((size_t)(bbase + 1024), 256);
    ushort* xh   = (ushort*)p;        // N*128 bf16 (25.6 MB)
    ushort* aggh = xh + (size_t)N * D;// N*128 bf16 (25.6 MB)
    size_t need_full = (size_t)((char*)(aggh + (size_t)N * D) - (char*)d_ws);
    const bool full = (ws_size >= need_full);

    if (full) {
        hipMemsetAsync(cnt, 0, (size_t)N * sizeof(int), stream);
        const int setup_threads = (N * (D / 8) > E) ? N * (D / 8) : E;
        setup_kernel<<<(setup_threads + 255) / 256, 256, 0, stream>>>(
            x, dst, Wl, Wr, xh, Wswhi, Wswlo, cnt, N, E);
        scan_partial<<<nblk, 256, 0, stream>>>(cnt, bsum, N);
        scan_base<<<1, 1024, 0, stream>>>(bsum, bbase, offsets, nblk, N);
        scan_final<<<nblk, 256, 0, stream>>>(cnt, bbase, offsets, cursor, N);
        fill_kernel<<<2048, 256, 0, stream>>>(src, dst, cursor, bucket, E, rn);
        agg_kernel<<<(N + 3) / 4, 256, 0, stream>>>(
            (const uint4*)xh, offsets, bucket, (uint4*)aggh, N);
        dense_kernel<<<(N + MT - 1) / MT, 256, 0, stream>>>(
            aggh, xh, Wswhi, Wswlo, bl, gam, bet, out, N);
    } else {
        // fallback: proven fp32 fused path (small ws)
        hipMemsetAsync(cnt, 0, (size_t)N * sizeof(int), stream);
        transpose_w<<<(D * D + 255) / 256, 256, 0, stream>>>(Wl, Wr, WlT, WrT);
        hist_kernel<<<(E + 255) / 256, 256, 0, stream>>>(dst, cnt, E);
        scan_partial<<<nblk, 256, 0, stream>>>(cnt, bsum, N);
        scan_base<<<1, 1024, 0, stream>>>(bsum, bbase, offsets, nblk, N);
        scan_final<<<nblk, 256, 0, stream>>>(cnt, bbase, offsets, cursor, N);
        fill_kernel<<<2048, 256, 0, stream>>>(src, dst, cursor, bucket, E, rn);
        fused_fb<<<(N + NBF - 1) / NBF, 256, 0, stream>>>(
            x, WlT, WrT, bl, gam, bet, offsets, bucket, out, N);
    }
}